// Round 1
// baseline (84.234 us; speedup 1.0000x reference)
//
#include <hip/hip_runtime.h>

#define T_TRIG 48
#define S_SPAN 128
#define NN (T_TRIG * S_SPAN)      // 6144 nodes
#define D 128                     // feature dim (= HEADS*HEAD_DIM = in dim)
#define DEG (S_SPAN + T_TRIG - 1) // 175 incoming edges per node

// ---------------------------------------------------------------------------
// GEMM  H = X @ W  (NNxD @ DxD), fused epilogue computing per-node attention
// scalars: asrc[n][h] = sum_d H[n][h*32+d]*att_s[h][d], adst likewise.
// Block: 256 threads = 16 (tx, col groups of 8) x 16 (ty, row pairs).
// Tile: 32 rows x 128 cols per block. W staged fully in LDS (64KB).
// ---------------------------------------------------------------------------
__global__ __launch_bounds__(256) void gemm_att_kernel(
    const float* __restrict__ X, const float* __restrict__ W,
    const float* __restrict__ att_s, const float* __restrict__ att_d,
    float* __restrict__ H, float* __restrict__ asrc, float* __restrict__ adst)
{
    __shared__ float wl[128 * 128];
    const int tid = threadIdx.x;
    {
        const float4* W4 = (const float4*)W;
        float4* wl4 = (float4*)wl;
        #pragma unroll
        for (int i = 0; i < 16; ++i)
            wl4[tid + i * 256] = W4[tid + i * 256];
    }
    __syncthreads();

    const int tx = tid & 15;
    const int ty = tid >> 4;
    const int i0 = blockIdx.x * 32 + ty * 2;  // two rows per thread
    const int j0 = tx * 8;                    // eight cols per thread

    float acc[2][8];
    #pragma unroll
    for (int a = 0; a < 2; ++a)
        #pragma unroll
        for (int b = 0; b < 8; ++b) acc[a][b] = 0.f;

    const float* x0 = X + i0 * D;
    for (int k = 0; k < D; k += 4) {
        float4 xa4 = *(const float4*)(x0 + k);
        float4 xb4 = *(const float4*)(x0 + D + k);
        float xa[4] = {xa4.x, xa4.y, xa4.z, xa4.w};
        float xb[4] = {xb4.x, xb4.y, xb4.z, xb4.w};
        #pragma unroll
        for (int kk = 0; kk < 4; ++kk) {
            const float* wr = &wl[(k + kk) * 128 + j0];
            float4 w0 = *(const float4*)(wr);
            float4 w1 = *(const float4*)(wr + 4);
            float wv[8] = {w0.x, w0.y, w0.z, w0.w, w1.x, w1.y, w1.z, w1.w};
            #pragma unroll
            for (int jj = 0; jj < 8; ++jj) {
                acc[0][jj] = fmaf(xa[kk], wv[jj], acc[0][jj]);
                acc[1][jj] = fmaf(xb[kk], wv[jj], acc[1][jj]);
            }
        }
    }

    // store H tile
    #pragma unroll
    for (int ii = 0; ii < 2; ++ii) {
        float4 o0 = {acc[ii][0], acc[ii][1], acc[ii][2], acc[ii][3]};
        float4 o1 = {acc[ii][4], acc[ii][5], acc[ii][6], acc[ii][7]};
        *(float4*)&H[(i0 + ii) * D + j0]     = o0;
        *(float4*)&H[(i0 + ii) * D + j0 + 4] = o1;
    }

    // attention scalars: head = j0/32; reduce over the 4 tx-lanes of one head
    const int head = tx >> 2;
    const int dbase = head * 32 + (tx & 3) * 8;
    float asv[8], adv[8];
    #pragma unroll
    for (int jj = 0; jj < 8; ++jj) {
        asv[jj] = att_s[dbase + jj];
        adv[jj] = att_d[dbase + jj];
    }
    #pragma unroll
    for (int ii = 0; ii < 2; ++ii) {
        float ps = 0.f, pd = 0.f;
        #pragma unroll
        for (int jj = 0; jj < 8; ++jj) {
            ps = fmaf(acc[ii][jj], asv[jj], ps);
            pd = fmaf(acc[ii][jj], adv[jj], pd);
        }
        ps += __shfl_xor(ps, 1); ps += __shfl_xor(ps, 2);
        pd += __shfl_xor(pd, 1); pd += __shfl_xor(pd, 2);
        if ((tx & 3) == 0) {
            asrc[(i0 + ii) * 4 + head] = ps;
            adst[(i0 + ii) * 4 + head] = pd;
        }
    }
}

// ---------------------------------------------------------------------------
// Aggregation: one block per destination node (6144 blocks, 128 threads).
// Sources for dst (r,c): row r, all 128 cols (incl self); column c, the 47
// rows t != r. Softmax over the 175 logits per head, then each thread owns
// one output feature f and accumulates weighted h[src][f], + bias, ELU.
// ---------------------------------------------------------------------------
__global__ __launch_bounds__(128) void agg_kernel(
    const float* __restrict__ H, const float4* __restrict__ asrc4,
    const float4* __restrict__ adst4, const float* __restrict__ bias,
    float* __restrict__ out)
{
    __shared__ float w[DEG + 1][4];
    __shared__ float inv_den[4];

    const int tid = threadIdx.x;
    const int n = blockIdx.x;
    const int r = n >> 7;
    const int c = n & 127;

    const float4 ad = adst4[n];
    for (int j = tid; j < DEG; j += 128) {
        int src;
        if (j < 128) {
            src = (r << 7) + j;
        } else {
            int t = j - 128;
            t += (t >= r) ? 1 : 0;
            src = (t << 7) + c;
        }
        float4 as = asrc4[src];
        float e0 = as.x + ad.x; e0 = e0 > 0.f ? e0 : 0.2f * e0;
        float e1 = as.y + ad.y; e1 = e1 > 0.f ? e1 : 0.2f * e1;
        float e2 = as.z + ad.z; e2 = e2 > 0.f ? e2 : 0.2f * e2;
        float e3 = as.w + ad.w; e3 = e3 > 0.f ? e3 : 0.2f * e3;
        float4 ev = {e0, e1, e2, e3};
        *(float4*)&w[j][0] = ev;
    }
    __syncthreads();

    // softmax normalizers: 32 lanes per head
    {
        const int head = tid >> 5;
        const int l = tid & 31;
        float m = -1e30f;
        for (int j = l; j < DEG; j += 32) m = fmaxf(m, w[j][head]);
        #pragma unroll
        for (int o = 16; o > 0; o >>= 1) m = fmaxf(m, __shfl_xor(m, o));
        float s = 0.f;
        for (int j = l; j < DEG; j += 32) {
            float v = __expf(w[j][head] - m);
            w[j][head] = v;
            s += v;
        }
        #pragma unroll
        for (int o = 16; o > 0; o >>= 1) s += __shfl_xor(s, o);
        if (l == 0) inv_den[head] = 1.f / s;
    }
    __syncthreads();

    const int f = tid;
    const int head = tid >> 5;
    float acc = 0.f;

    const float* hrow = H + (r << 7) * D + f;   // row sources: +j*D
    #pragma unroll 8
    for (int j = 0; j < S_SPAN; ++j)
        acc = fmaf(w[j][head], hrow[j * D], acc);

    const float* hcol = H + c * D + f;          // col sources: +t*S*D
    #pragma unroll 4
    for (int j2 = 0; j2 < T_TRIG - 1; ++j2) {
        int t = j2 + ((j2 >= r) ? 1 : 0);
        acc = fmaf(w[128 + j2][head], hcol[t * (S_SPAN * D)], acc);
    }

    acc = acc * inv_den[head] + bias[f];
    out[n * D + f] = acc > 0.f ? acc : (__expf(acc) - 1.f);
}

// ---------------------------------------------------------------------------
extern "C" void kernel_launch(void* const* d_in, const int* in_sizes, int n_in,
                              void* d_out, int out_size, void* d_ws, size_t ws_size,
                              hipStream_t stream)
{
    const float* pe  = (const float*)d_in[0];   // [1,48,128,128] == [6144,128]
    const float* W1  = (const float*)d_in[1];
    const float* as1 = (const float*)d_in[2];
    const float* ad1 = (const float*)d_in[3];
    const float* b1  = (const float*)d_in[4];
    const float* W2  = (const float*)d_in[5];
    const float* as2 = (const float*)d_in[6];
    const float* ad2 = (const float*)d_in[7];
    const float* b2  = (const float*)d_in[8];
    float* out = (float*)d_out;

    char* ws = (char*)d_ws;
    float* H    = (float*)(ws);                                  // 3 MB
    float* X2   = (float*)(ws + (size_t)NN * D * 4);             // 3 MB
    float* asrc = (float*)(ws + (size_t)2 * NN * D * 4);         // 96 KB
    float* adst = (float*)(ws + (size_t)2 * NN * D * 4 + (size_t)NN * 4 * 4);

    // layer 1
    gemm_att_kernel<<<dim3(NN / 32), dim3(256), 0, stream>>>(pe, W1, as1, ad1, H, asrc, adst);
    agg_kernel<<<dim3(NN), dim3(128), 0, stream>>>(H, (const float4*)asrc, (const float4*)adst, b1, X2);
    // layer 2
    gemm_att_kernel<<<dim3(NN / 32), dim3(256), 0, stream>>>(X2, W2, as2, ad2, H, asrc, adst);
    agg_kernel<<<dim3(NN), dim3(128), 0, stream>>>(H, (const float4*)asrc, (const float4*)adst, b2, out);
}